// Round 12
// baseline (1554.051 us; speedup 1.0000x reference)
//
#include <hip/hip_runtime.h>
#include <hip/hip_bf16.h>
#include <math.h>

#define Bc 4
#define Tc 512
#define Sc 1536          // 3*T
#define Hc 1024
#define NHc 16
#define Dc 64
#define FFc 4096
#define Lc 4
#define Mrows (Bc*Tc*3)  // 6144
#define LN_EPS 1e-5f

typedef __attribute__((ext_vector_type(4))) float  f32x4;
typedef __attribute__((ext_vector_type(8))) short  s16x8;
typedef __attribute__((ext_vector_type(4))) short  s16x4;

__device__ __forceinline__ short f2b(float f) {
    union { __hip_bfloat16 h; short s; } u;
    u.h = __float2bfloat16(f);
    return u.s;
}

__device__ __forceinline__ float b2f(short s) {
    union { unsigned u; float f; } v;
    v.u = ((unsigned)(unsigned short)s) << 16;
    return v.f;
}

__device__ __forceinline__ void gload16(const void* g, void* l) {
    __builtin_amdgcn_global_load_lds(
        (const __attribute__((address_space(1))) void*)g,
        (__attribute__((address_space(3))) void*)l, 16, 0, 0);
}

// ---------------------------------------------------------------------------
// Embedding
// ---------------------------------------------------------------------------
__global__ __launch_bounds__(256) void embed_kernel(
    const float* __restrict__ states, const float* __restrict__ rtg,
    const int* __restrict__ timesteps, const int* __restrict__ actions,
    const float* __restrict__ ett, const float* __restrict__ eat,
    const float* __restrict__ Wrtg, const float* __restrict__ brtg,
    const float* __restrict__ Wst, const float* __restrict__ bst,
    float* __restrict__ h)
{
    const int bt = blockIdx.x;
    const int b = bt / Tc, t = bt % Tc;
    const int ts = timesteps[bt];
    const int ac = actions[bt];
    const float rv = rtg[bt];
    const float* te = ett + (size_t)ts * Hc;
    const float* ea = eat + (size_t)ac * Hc;
    __shared__ float sst[17];
    if (threadIdx.x < 17) sst[threadIdx.x] = states[bt * 17 + threadIdx.x];
    __syncthreads();
    float* hr = h + ((size_t)b * Sc + 3 * t) * Hc;
    for (int j = threadIdx.x; j < Hc; j += 256) {
        const float tej = te[j];
        hr[j] = rv * Wrtg[j] + brtg[j] + tej;
        float sv = bst[j];
        #pragma unroll
        for (int qx = 0; qx < 17; ++qx) sv += sst[qx] * Wst[qx * Hc + j];
        hr[Hc + j] = sv + tej;
        hr[2 * Hc + j] = ea[j] + tej;
    }
}

// ---------------------------------------------------------------------------
// Fused residual-add + LayerNorm; add is bf16 (or nullptr); emits bf16 hb.
// ---------------------------------------------------------------------------
__global__ __launch_bounds__(256) void resln_kernel(float* __restrict__ h,
                                                    const short* __restrict__ add,
                                                    short* __restrict__ hb)
{
    const size_t row = blockIdx.x;
    float4* hr = reinterpret_cast<float4*>(h + row * Hc);
    const int tid = threadIdx.x;
    float4 x = hr[tid];
    if (add != nullptr) {
        const s16x4 a = *(const s16x4*)&add[row * Hc + tid * 4];
        x.x += b2f(a[0]); x.y += b2f(a[1]); x.z += b2f(a[2]); x.w += b2f(a[3]);
    }
    float s1 = x.x + x.y + x.z + x.w;
    float s2 = x.x*x.x + x.y*x.y + x.z*x.z + x.w*x.w;
    #pragma unroll
    for (int off = 32; off > 0; off >>= 1) {
        s1 += __shfl_xor(s1, off);
        s2 += __shfl_xor(s2, off);
    }
    __shared__ float r1[4], r2[4];
    const int wv = tid >> 6, lane = tid & 63;
    if (lane == 0) { r1[wv] = s1; r2[wv] = s2; }
    __syncthreads();
    s1 = r1[0] + r1[1] + r1[2] + r1[3];
    s2 = r2[0] + r2[1] + r2[2] + r2[3];
    const float mean = s1 * (1.0f / Hc);
    const float var  = s2 * (1.0f / Hc) - mean * mean;
    const float rs = rsqrtf(var + LN_EPS);
    x.x = (x.x - mean) * rs; x.y = (x.y - mean) * rs;
    x.z = (x.z - mean) * rs; x.w = (x.w - mean) * rs;
    hr[tid] = x;
    if (hb != nullptr) {
        s16x4 o; o[0] = f2b(x.x); o[1] = f2b(x.y); o[2] = f2b(x.z); o[3] = f2b(x.w);
        *(s16x4*)&hb[row * Hc + tid * 4] = o;
    }
}

// ---------------------------------------------------------------------------
// Merged per-layer weight convert+transpose: 3072 64x64 tiles.
// ---------------------------------------------------------------------------
__global__ __launch_bounds__(256) void wconv_all_kernel(
    const float* __restrict__ Wq, const float* __restrict__ Wk,
    const float* __restrict__ Wv, const float* __restrict__ Wo,
    const float* __restrict__ W1, const float* __restrict__ W2,
    short* __restrict__ wqkv_t, short* __restrict__ wo_t,
    short* __restrict__ w1_t, short* __restrict__ w2_t)
{
    __shared__ float Ls[64][68];
    const int blk = blockIdx.x;
    const float* src; short* dst; int N, dstStride, dstRow0, tx, ty;
    if (blk < 1024) {
        const int m = blk >> 8;
        const int local = blk & 255;
        tx = local & 15; ty = local >> 4;
        N = 1024; dstStride = 1024;
        if (m == 0)      { src = Wq; dst = wqkv_t; dstRow0 = 0; }
        else if (m == 1) { src = Wk; dst = wqkv_t; dstRow0 = 1024; }
        else if (m == 2) { src = Wv; dst = wqkv_t; dstRow0 = 2048; }
        else             { src = Wo; dst = wo_t;   dstRow0 = 0; }
    } else if (blk < 2048) {
        const int local = blk - 1024;
        tx = local & 63; ty = local >> 6;
        src = W1; dst = w1_t; N = 4096; dstStride = 1024; dstRow0 = 0;
    } else {
        const int local = blk - 2048;
        tx = local & 15; ty = local >> 4;
        src = W2; dst = w2_t; N = 1024; dstStride = 4096; dstRow0 = 0;
    }
    const int n0 = tx * 64, k0 = ty * 64;
    const int tid = threadIdx.x;
    #pragma unroll
    for (int it = 0; it < 4; ++it) {
        const int idx = tid + 256 * it;
        const int r = idx >> 4, c4 = idx & 15;
        *(f32x4*)&Ls[r][c4 * 4] = *(const f32x4*)(src + (size_t)(k0 + r) * N + n0 + c4 * 4);
    }
    __syncthreads();
    #pragma unroll
    for (int it = 0; it < 2; ++it) {
        const int idx = tid + 256 * it;
        const int n = idx & 63, k8 = idx >> 6;
        s16x8 o;
        #pragma unroll
        for (int j = 0; j < 8; ++j) o[j] = f2b(Ls[k8 * 8 + j][n]);
        *(s16x8*)(dst + (size_t)(dstRow0 + n0 + n) * dstStride + k0 + k8 * 8) = o;
    }
}

// ---------------------------------------------------------------------------
// Pack QKV biases
// ---------------------------------------------------------------------------
__global__ __launch_bounds__(256) void biaspack_kernel(
    const float* __restrict__ bq, const float* __restrict__ bk,
    const float* __restrict__ bv, float* __restrict__ pb)
{
    const int idx = blockIdx.x * 256 + threadIdx.x;
    const int l = idx / 3072, j = idx % 3072;
    float v;
    if (j < 1024) v = bq[l * 1024 + j];
    else if (j < 2048) v = bk[l * 1024 + j - 1024];
    else v = bv[l * 1024 + j - 2048];
    pb[idx] = v;
}

// ---------------------------------------------------------------------------
// Heads weight pack
// ---------------------------------------------------------------------------
__global__ __launch_bounds__(256) void headspack_kernel(
    const float* __restrict__ Wps, const float* __restrict__ bps,
    const float* __restrict__ Wpr, const float* __restrict__ bpr,
    const float* __restrict__ Wpa, const float* __restrict__ bpa,
    short* __restrict__ Wha, short* __restrict__ Whb,
    float* __restrict__ biasA, float* __restrict__ biasB)
{
    const int n = blockIdx.x & 63, set = blockIdx.x >> 6;   // grid 128
    const int tid = threadIdx.x;
    if (tid == 0) {
        if (set == 0) biasA[n] = (n < 17) ? bps[n] : (n == 17 ? bpr[0] : 0.f);
        else          biasB[n] = (n < 18) ? bpa[n] : 0.f;
    }
    short* dst = (set == 0 ? Wha : Whb) + (size_t)n * 1024;
    for (int k = tid; k < 1024; k += 256) {
        float v;
        if (set == 0) v = (n < 17) ? Wps[(size_t)k * 17 + n] : (n == 17 ? Wpr[k] : 0.f);
        else          v = (n < 18) ? Wpa[(size_t)k * 18 + n] : 0.f;
        dst[k] = f2b(v);
    }
}

// ---------------------------------------------------------------------------
// Heads gather
// ---------------------------------------------------------------------------
__global__ __launch_bounds__(256) void headsgather_kernel(
    const float* __restrict__ scrA, const float* __restrict__ scrB,
    float* __restrict__ out)
{
    const int idx = blockIdx.x * 256 + threadIdx.x;
    if (idx >= 2048 * 36) return;
    const int bt = idx / 36, j = idx % 36;
    if (j < 17)      out[bt * 17 + j] = scrA[bt * 64 + j];
    else if (j < 35) out[2048 * 17 + bt * 18 + (j - 17)] = scrB[bt * 64 + (j - 17)];
    else             out[2048 * 35 + bt] = scrA[bt * 64 + 17];
}

// ---------------------------------------------------------------------------
// 128-tile bf16 GEMM, 3-buffer single-barrier rotation + counted vmcnt +
// both-sides LDS swizzle. Per K-step: vmcnt(4) -> barrier -> stage(t+2)
// into buf[(t+2)%3] (== buf[(t-1)%3], whose reads all waves completed via
// their own lgkmcnt(0) before reaching this barrier) -> ds_read buf[t%3]
// -> lgkmcnt(0) -> sched_barrier -> MFMA.  ONE barrier per K-step.
// VT_FUSE (QKV only): cols >= 2048 written transposed to vt[bh][d][s].
// ---------------------------------------------------------------------------
template<int BN, int DO_GELU, int OUTBF16, int VT_FUSE>
__global__ __launch_bounds__(256, 4) void gemm_bb(
    const short* __restrict__ A, const short* __restrict__ Bt,
    const float* __restrict__ bias, void* __restrict__ Cv,
    int M, int N, int K, int arm, int aro, short* __restrict__ vt)
{
    constexpr int NJ = BN / 32;
    __shared__ short As[3 * 128 * 32];
    __shared__ short Bs[3 * BN * 32];
    const int tid = threadIdx.x, lane = tid & 63, wid = tid >> 6;
    const int wr = wid >> 1, wc = wid & 1;
    const int g = lane >> 4, ql = lane & 15;
    const int m0 = blockIdx.y * 128, n0 = blockIdx.x * BN;

    const int crow = lane >> 2;
    const int csw  = ((lane & 3) ^ ((crow >> 1) & 3)) * 8;

    const short* Ag0 = A + ((size_t)arm * (m0 + wid * 32 + crow) + aro) * K + csw;
    const short* Ag1 = A + ((size_t)arm * (m0 + wid * 32 + 16 + crow) + aro) * K + csw;
    const int a0off = (wid * 32) * 32;
    const int a1off = (wid * 32 + 16) * 32;

    const short* Bg0; const short* Bg1 = nullptr;
    int b0off = 0, b1off = 0;
    if constexpr (BN == 128) {
        Bg0 = Bt + (size_t)(n0 + wid * 32 + crow) * K + csw;
        Bg1 = Bt + (size_t)(n0 + wid * 32 + 16 + crow) * K + csw;
        b0off = (wid * 32) * 32;
        b1off = (wid * 32 + 16) * 32;
    } else {
        Bg0 = Bt + (size_t)(n0 + wid * 16 + crow) * K + csw;
        b0off = (wid * 16) * 32;
    }

    auto stage = [&](int buf, int k0) {
        short* Ab = &As[buf * (128 * 32)];
        short* Bb = &Bs[buf * (BN * 32)];
        gload16(Ag0 + k0, Ab + a0off);
        gload16(Ag1 + k0, Ab + a1off);
        gload16(Bg0 + k0, Bb + b0off);
        if constexpr (BN == 128) gload16(Bg1 + k0, Bb + b1off);
    };

    const int rslot = (g ^ ((ql >> 1) & 3)) * 8;
    const int aoffr = (wr * 64 + ql) * 32 + rslot;
    const int boffr = (wc * (BN / 2) + ql) * 32 + rslot;

    f32x4 acc[4][NJ] = {};
    const int NT = K / 32;
    stage(0, 0);
    stage(1, 32);
    int buf = 0;
    for (int t = 0; t < NT; ++t) {
        if (t + 1 < NT) {
            if constexpr (BN == 128) asm volatile("s_waitcnt vmcnt(4)" ::: "memory");
            else                     asm volatile("s_waitcnt vmcnt(3)" ::: "memory");
        } else {
            asm volatile("s_waitcnt vmcnt(0)" ::: "memory");
        }
        __builtin_amdgcn_s_barrier();     // all waves done reading buf[(t-1)%3]

        if (t + 2 < NT) {
            const int nb = (buf + 2 >= 3) ? buf - 1 : buf + 2;
            stage(nb, (t + 2) * 32);      // overwrites buf[(t-1)%3] -- safe
        }

        const short* Acur = &As[buf * (128 * 32)];
        const short* Bcur = &Bs[buf * (BN * 32)];
        s16x8 af[4], bfr[NJ];
        #pragma unroll
        for (int mi = 0; mi < 4; ++mi)
            af[mi] = *(const s16x8*)&Acur[aoffr + mi * (16 * 32)];
        #pragma unroll
        for (int nj = 0; nj < NJ; ++nj)
            bfr[nj] = *(const s16x8*)&Bcur[boffr + nj * (16 * 32)];

        asm volatile("s_waitcnt lgkmcnt(0)" ::: "memory");
        __builtin_amdgcn_sched_barrier(0);

        #pragma unroll
        for (int mi = 0; mi < 4; ++mi)
            #pragma unroll
            for (int nj = 0; nj < NJ; ++nj)
                acc[mi][nj] = __builtin_amdgcn_mfma_f32_16x16x32_bf16(
                    af[mi], bfr[nj], acc[mi][nj], 0, 0, 0);
        buf = (buf + 1 == 3) ? 0 : buf + 1;
    }

    #pragma unroll
    for (int mi = 0; mi < 4; ++mi) {
        #pragma unroll
        for (int nj = 0; nj < NJ; ++nj) {
            const int col = n0 + wc * (BN / 2) + nj * 16 + ql;
            const float bv = bias[col];
            float vals[4];
            #pragma unroll
            for (int r = 0; r < 4; ++r) {
                float v = acc[mi][nj][r] + bv;
                if constexpr (DO_GELU)
                    v = 0.5f * v * (1.0f + erff(v * 0.70710678118654752f));
                vals[r] = v;
            }
            if (VT_FUSE && col >= 2048) {
                const int row0 = m0 + wr * 64 + mi * 16 + g * 4;
                const int b = row0 / Sc, s = row0 % Sc;
                const int cc = col - 2048, hh = cc >> 6, d = cc & 63;
                s16x4 o;
                #pragma unroll
                for (int r = 0; r < 4; ++r) o[r] = f2b(vals[r]);
                *(s16x4*)(vt + (((size_t)(b * NHc + hh) * 64 + d) * Sc + s)) = o;
            } else {
                #pragma unroll
                for (int r = 0; r < 4; ++r) {
                    const int row = m0 + wr * 64 + mi * 16 + g * 4 + r;
                    if constexpr (OUTBF16)
                        ((short*)Cv)[(size_t)row * N + col] = f2b(vals[r]);
                    else
                        ((float*)Cv)[(size_t)row * N + col] = vals[r];
                }
            }
        }
    }
}

// ---------------------------------------------------------------------------
// MFMA flash attention v3 (round-9 proven)
// ---------------------------------------------------------------------------
__global__ __launch_bounds__(256) void attn_kernel(
    const short* __restrict__ qg, const short* __restrict__ kg,
    const short* __restrict__ vtg, short* __restrict__ og, int qks)
{
    const int nqt = Sc / 64;
    const int blk = blockIdx.x;
    const int bh = blk / nqt;
    const int qt = (nqt - 1) - (blk % nqt);   // longest blocks first
    const int b = bh / NHc, hh = bh % NHc;
    const int tid = threadIdx.x, lane = tid & 63, w = tid >> 6;
    const int g = lane >> 4, ql = lane & 15;

    __shared__ short Ks[2][64 * 64];
    __shared__ short Vs[2][64 * 64];
    __shared__ short Qs[64][72];
    __shared__ short Ps[4][16][72];

    const size_t baseq = ((size_t)b * Sc) * qks + hh * Dc;

    #pragma unroll
    for (int i = 0; i < 2; ++i) {
        const int idx = tid + 256 * i;
        const int r = idx >> 3, c8 = idx & 7;
        *(s16x8*)&Qs[r][c8 * 8] =
            *(const s16x8*)(qg + baseq + (size_t)(qt * 64 + r) * qks + c8 * 8);
    }
    __syncthreads();
    const s16x8 bq0 = *(const s16x8*)&Qs[w * 16 + ql][g * 8];
    const s16x8 bq1 = *(const s16x8*)&Qs[w * 16 + ql][32 + g * 8];

    const int srow = lane >> 3;               // 0..7
    const int r0 = w * 8 + srow;
    const int r1 = 32 + w * 8 + srow;
    const int g0 = ((lane & 7) ^ (r0 & 7)) * 8;
    const int g1 = ((lane & 7) ^ (r1 & 7)) * 8;
    const short* kg0 = kg + baseq + (size_t)r0 * qks + g0;
    const short* kg1 = kg + baseq + (size_t)r1 * qks + g1;
    const short* vg0 = vtg + ((size_t)bh * 64 + r0) * Sc + g0;
    const short* vg1 = vtg + ((size_t)bh * 64 + r1) * Sc + g1;

    auto stageKV = [&](int buf, int kt) {
        const size_t ko = (size_t)kt * 64 * qks;
        const size_t vo = (size_t)kt * 64;
        gload16(kg0 + ko, &Ks[buf][w * 512]);
        gload16(kg1 + ko, &Ks[buf][2048 + w * 512]);
        gload16(vg0 + vo, &Vs[buf][w * 512]);
        gload16(vg1 + vo, &Vs[buf][2048 + w * 512]);
    };

    const int kx = ql & 7;
    const int gr0 = (g ^ kx) * 8;
    const int gr1 = ((4 + g) ^ kx) * 8;

    f32x4 acc_o[4] = {};
    float m = -1e30f, l = 0.f;
    const int qrow = qt * 64 + w * 16 + ql;

    stageKV(0, 0);
    for (int kt = 0; kt <= qt; ++kt) {
        const int buf = kt & 1;
        if (kt < qt) {
            stageKV(buf ^ 1, kt + 1);
            asm volatile("s_waitcnt vmcnt(4)" ::: "memory");
        } else {
            asm volatile("s_waitcnt vmcnt(0)" ::: "memory");
        }
        __builtin_amdgcn_s_barrier();

        s16x8 ka0[4], ka1[4], vv0[4], vv1[4];
        #pragma unroll
        for (int mi = 0; mi < 4; ++mi) {
            ka0[mi] = *(const s16x8*)&Ks[buf][(mi * 16 + ql) * 64 + gr0];
            ka1[mi] = *(const s16x8*)&Ks[buf][(mi * 16 + ql) * 64 + gr1];
            vv0[mi] = *(const s16x8*)&Vs[buf][(mi * 16 + ql) * 64 + gr0];
            vv1[mi] = *(const s16x8*)&Vs[buf][(mi * 16 + ql) * 64 + gr1];
        }
        asm volatile("s_waitcnt lgkmcnt(0)" ::: "memory");
        __builtin_amdgcn_sched_barrier(0);
        __builtin_amdgcn_s_barrier();

        f32x4 sacc[4] = {};
        #pragma unroll
        for (int mi = 0; mi < 4; ++mi) {
            sacc[mi] = __builtin_amdgcn_mfma_f32_16x16x32_bf16(ka0[mi], bq0, sacc[mi], 0, 0, 0);
            sacc[mi] = __builtin_amdgcn_mfma_f32_16x16x32_bf16(ka1[mi], bq1, sacc[mi], 0, 0, 0);
        }

        float pv[16];
        float pm = -1e30f;
        #pragma unroll
        for (int mi = 0; mi < 4; ++mi)
            #pragma unroll
            for (int r = 0; r < 4; ++r) {
                const int kv = kt * 64 + mi * 16 + g * 4 + r;
                const float s = (kv <= qrow) ? sacc[mi][r] * 0.125f : -1e30f;
                pv[mi * 4 + r] = s;
                pm = fmaxf(pm, s);
            }
        pm = fmaxf(pm, __shfl_xor(pm, 16));
        pm = fmaxf(pm, __shfl_xor(pm, 32));
        const float m2 = fmaxf(m, pm);
        const float corr = __expf(m - m2);
        m = m2;
        float ps = 0.f;
        #pragma unroll
        for (int i = 0; i < 16; ++i) { pv[i] = __expf(pv[i] - m2); ps += pv[i]; }
        ps += __shfl_xor(ps, 16);
        ps += __shfl_xor(ps, 32);
        l = l * corr + ps;

        #pragma unroll
        for (int mi = 0; mi < 4; ++mi) {
            s16x4 pw;
            #pragma unroll
            for (int r = 0; r < 4; ++r) pw[r] = f2b(pv[mi * 4 + r]);
            *(s16x4*)&Ps[w][ql][mi * 16 + g * 4] = pw;
        }

        float corr_r[4];
        #pragma unroll
        for (int r = 0; r < 4; ++r) corr_r[r] = __shfl(corr, g * 4 + r);
        #pragma unroll
        for (int nj = 0; nj < 4; ++nj)
            #pragma unroll
            for (int r = 0; r < 4; ++r) acc_o[nj][r] *= corr_r[r];

        const s16x8 pa0 = *(const s16x8*)&Ps[w][ql][g * 8];
        const s16x8 pa1 = *(const s16x8*)&Ps[w][ql][32 + g * 8];
        #pragma unroll
        for (int nj = 0; nj < 4; ++nj) {
            acc_o[nj] = __builtin_amdgcn_mfma_f32_16x16x32_bf16(pa0, vv0[nj], acc_o[nj], 0, 0, 0);
            acc_o[nj] = __builtin_amdgcn_mfma_f32_16x16x32_bf16(pa1, vv1[nj], acc_o[nj], 0, 0, 0);
        }
    }

    const float rl = 1.0f / l;
    float rl_r[4];
    #pragma unroll
    for (int r = 0; r < 4; ++r) rl_r[r] = __shfl(rl, g * 4 + r);
    const size_t baseo = ((size_t)b * Sc) * Hc + hh * Dc;
    #pragma unroll
    for (int nj = 0; nj < 4; ++nj)
        #pragma unroll
        for (int r = 0; r < 4; ++r) {
            const int qr = qt * 64 + w * 16 + g * 4 + r;
            og[baseo + (size_t)qr * Hc + nj * 16 + ql] = f2b(acc_o[nj][r] * rl_r[r]);
        }
}

// ---------------------------------------------------------------------------
extern "C" void kernel_launch(void* const* d_in, const int* in_sizes, int n_in,
                              void* d_out, int out_size, void* d_ws, size_t ws_size,
                              hipStream_t stream)
{
    const float* states = (const float*)d_in[0];
    const float* rtg    = (const float*)d_in[1];
    const int*   timesteps = (const int*)d_in[2];
    const int*   actions   = (const int*)d_in[3];
    const float* ett  = (const float*)d_in[5];
    const float* eat  = (const float*)d_in[6];
    const float* Wrtg = (const float*)d_in[7];
    const float* brtg = (const float*)d_in[8];
    const float* Wst  = (const float*)d_in[9];
    const float* bst  = (const float*)d_in[10];
    const float* Wq = (const float*)d_in[11];
    const float* bq = (const float*)d_in[12];
    const float* Wk = (const float*)d_in[13];
    const float* bk = (const float*)d_in[14];
    const float* Wv = (const float*)d_in[15];
    const float* bv = (const float*)d_in[16];
    const float* Wo = (const float*)d_in[17];
    const float* bo = (const float*)d_in[18];
    const float* W1 = (const float*)d_in[19];
    const float* b1 = (const float*)d_in[20];
    const float* W2 = (const float*)d_in[21];
    const float* b2 = (const float*)d_in[22];
    const float* Wpr = (const float*)d_in[23];
    const float* bpr = (const float*)d_in[24];
    const float* Wps = (const float*)d_in[25];
    const float* bps = (const float*)d_in[26];
    const float* Wpa = (const float*)d_in[27];
    const float* bpa = (const float*)d_in[28];
    float* out = (float*)d_out;

    char* wsb = (char*)d_ws;
    const size_t MH = (size_t)Mrows * Hc;            // 6,291,456 elems
    const int nAttnBlk = Bc * NHc * (Sc / 64);       // 1536

    const size_t off_h    = 0;                        // f32  [M][H]
    const size_t off_hb   = off_h    + MH * 4;        // bf16 [M][H]
    const size_t off_qkv  = off_hb   + MH * 2;        // bf16 [M][3H]
    const size_t off_vt   = off_qkv  + MH * 6;        // bf16 [BH][D][S]
    const size_t off_ob   = off_vt   + MH * 2;        // bf16 [M][H]
    const size_t off_rb   = off_ob   + MH * 2;        // bf16 [M][H] (+ heads f32 scratch)
    const size_t off_wl   = off_rb   + MH * 4;        // bf16 per-layer weights
    const size_t wl_qkv   = 0;
    const size_t wl_wo    = wl_qkv + (size_t)3072 * 1024 * 2;
    const size_t wl_w1    = wl_wo  + (size_t)1024 * 1024 * 2;
    const size_t wl_w2    = wl_w1  + (size_t)4096 * 1024 * 2;
    const size_t wl_bytes = wl_w2  + (size_t)1024 * 4096 * 2;
    const size_t off_pb   = off_wl + wl_bytes;        // f32 [L][3072]

    float* h   = (float*)(wsb + off_h);
    short* hb  = (short*)(wsb + off_hb);
    short* qkv = (short*)(wsb + off_qkv);
    short* vt  = (short*)(wsb + off_vt);
    short* ob  = (short*)(wsb + off_ob);
    short* rb  = (short*)(wsb + off_rb);           // bf16 residual buffer
    short* gb  = qkv;                              // bf16 [M][4096], spans qkv..vt
    short* wqkv_t = (short*)(wsb + off_wl + wl_qkv);
    short* wo_t   = (short*)(wsb + off_wl + wl_wo);
    short* w1_t   = (short*)(wsb + off_wl + wl_w1);
    short* w2_t   = (short*)(wsb + off_wl + wl_w2);
    float* pb     = (float*)(wsb + off_pb);
    short* Wha   = ob;                             // heads scratch (ob free at end)
    short* Whb   = ob + 64 * 1024;
    float* biasA = (float*)(ob + 2 * 64 * 1024);
    float* biasB = biasA + 64;
    float* scrA  = (float*)(wsb + off_rb + MH * 2);   // f32 [2048][64] x2, after rb
    float* scrB  = scrA + 2048 * 64;

    biaspack_kernel<<<Lc * 12, 256, 0, stream>>>(bq, bk, bv, pb);
    embed_kernel<<<Bc * Tc, 256, 0, stream>>>(states, rtg, timesteps, actions,
                                              ett, eat, Wrtg, brtg, Wst, bst, h);
    resln_kernel<<<Mrows, 256, 0, stream>>>(h, nullptr, hb);

    const dim3 gQKV(3072 / 128, Mrows / 128);     // (24,48)
    const dim3 gFF1(FFc / 128, Mrows / 128);      // (32,48)
    const dim3 gN1K(1024 / 128, Mrows / 128);     // (8,48)

    for (int i = 0; i < Lc; ++i) {
        const size_t wofH = (size_t)i * Hc * Hc;
        const size_t wofF = (size_t)i * Hc * FFc;
        wconv_all_kernel<<<3072, 256, 0, stream>>>(
            Wq + wofH, Wk + wofH, Wv + wofH, Wo + wofH, W1 + wofF, W2 + wofF,
            wqkv_t, wo_t, w1_t, w2_t);

        // QKV with fused V^T emission (V region bypasses qkv buffer)
        gemm_bb<128,0,1,1><<<gQKV, 256, 0, stream>>>(hb, wqkv_t, pb + i * 3072, qkv, Mrows, 3072, 1024, 1, 0, vt);
        attn_kernel<<<nAttnBlk, 256, 0, stream>>>(qkv, qkv + 1024, vt, ob, 3072);
        gemm_bb<128,0,1,0><<<gN1K, 256, 0, stream>>>(ob, wo_t, bo + i * Hc, rb, Mrows, 1024, 1024, 1, 0, nullptr);
        resln_kernel<<<Mrows, 256, 0, stream>>>(h, rb, hb);

        gemm_bb<128,1,1,0><<<gFF1, 256, 0, stream>>>(hb, w1_t, b1 + i * FFc, gb, Mrows, 4096, 1024, 1, 0, nullptr);
        gemm_bb<128,0,1,0><<<gN1K, 256, 0, stream>>>(gb, w2_t, b2 + i * Hc, rb, Mrows, 1024, 4096, 1, 0, nullptr);
        resln_kernel<<<Mrows, 256, 0, stream>>>(h, rb, hb);
    }

    // heads: row(hb) = 3*m + {2:h_a, 1:h_s}
    headspack_kernel<<<128, 256, 0, stream>>>(Wps, bps, Wpr, bpr, Wpa, bpa,
                                              Wha, Whb, biasA, biasB);
    gemm_bb<64,0,0,0><<<dim3(1, 16), 256, 0, stream>>>(hb, Wha, biasA, scrA, 2048, 64, 1024, 3, 2, nullptr);
    gemm_bb<64,0,0,0><<<dim3(1, 16), 256, 0, stream>>>(hb, Whb, biasB, scrB, 2048, 64, 1024, 3, 1, nullptr);
    headsgather_kernel<<<288, 256, 0, stream>>>(scrA, scrB, out);
}

// Round 13
// 1384.807 us; speedup vs baseline: 1.1222x; 1.1222x over previous
//
#include <hip/hip_runtime.h>
#include <hip/hip_bf16.h>
#include <math.h>

#define Bc 4
#define Tc 512
#define Sc 1536          // 3*T
#define Hc 1024
#define NHc 16
#define Dc 64
#define FFc 4096
#define Lc 4
#define Mrows (Bc*Tc*3)  // 6144
#define LN_EPS 1e-5f

typedef __attribute__((ext_vector_type(4))) float  f32x4;
typedef __attribute__((ext_vector_type(8))) short  s16x8;
typedef __attribute__((ext_vector_type(4))) short  s16x4;

__device__ __forceinline__ short f2b(float f) {
    union { __hip_bfloat16 h; short s; } u;
    u.h = __float2bfloat16(f);
    return u.s;
}

__device__ __forceinline__ float b2f(short s) {
    union { unsigned u; float f; } v;
    v.u = ((unsigned)(unsigned short)s) << 16;
    return v.f;
}

__device__ __forceinline__ float gelu_tanh(float x) {
    // max |delta| vs exact erf-GELU ~3e-4 (<< 0.058 threshold)
    const float z = 0.7978845608f * (x + 0.044715f * x * x * x);
    const float e = __expf(-2.0f * fabsf(z));
    float th = (1.0f - e) / (1.0f + e);
    th = copysignf(th, z);
    return 0.5f * x * (1.0f + th);
}

__device__ __forceinline__ void gload16(const void* g, void* l) {
    __builtin_amdgcn_global_load_lds(
        (const __attribute__((address_space(1))) void*)g,
        (__attribute__((address_space(3))) void*)l, 16, 0, 0);
}

// ---------------------------------------------------------------------------
// Embedding
// ---------------------------------------------------------------------------
__global__ __launch_bounds__(256) void embed_kernel(
    const float* __restrict__ states, const float* __restrict__ rtg,
    const int* __restrict__ timesteps, const int* __restrict__ actions,
    const float* __restrict__ ett, const float* __restrict__ eat,
    const float* __restrict__ Wrtg, const float* __restrict__ brtg,
    const float* __restrict__ Wst, const float* __restrict__ bst,
    float* __restrict__ h)
{
    const int bt = blockIdx.x;
    const int b = bt / Tc, t = bt % Tc;
    const int ts = timesteps[bt];
    const int ac = actions[bt];
    const float rv = rtg[bt];
    const float* te = ett + (size_t)ts * Hc;
    const float* ea = eat + (size_t)ac * Hc;
    __shared__ float sst[17];
    if (threadIdx.x < 17) sst[threadIdx.x] = states[bt * 17 + threadIdx.x];
    __syncthreads();
    float* hr = h + ((size_t)b * Sc + 3 * t) * Hc;
    for (int j = threadIdx.x; j < Hc; j += 256) {
        const float tej = te[j];
        hr[j] = rv * Wrtg[j] + brtg[j] + tej;
        float sv = bst[j];
        #pragma unroll
        for (int qx = 0; qx < 17; ++qx) sv += sst[qx] * Wst[qx * Hc + j];
        hr[Hc + j] = sv + tej;
        hr[2 * Hc + j] = ea[j] + tej;
    }
}

// ---------------------------------------------------------------------------
// Fused residual-add + LayerNorm; add is bf16 (or nullptr); emits bf16 hb.
// ---------------------------------------------------------------------------
__global__ __launch_bounds__(256) void resln_kernel(float* __restrict__ h,
                                                    const short* __restrict__ add,
                                                    short* __restrict__ hb)
{
    const size_t row = blockIdx.x;
    float4* hr = reinterpret_cast<float4*>(h + row * Hc);
    const int tid = threadIdx.x;
    float4 x = hr[tid];
    if (add != nullptr) {
        const s16x4 a = *(const s16x4*)&add[row * Hc + tid * 4];
        x.x += b2f(a[0]); x.y += b2f(a[1]); x.z += b2f(a[2]); x.w += b2f(a[3]);
    }
    float s1 = x.x + x.y + x.z + x.w;
    float s2 = x.x*x.x + x.y*x.y + x.z*x.z + x.w*x.w;
    #pragma unroll
    for (int off = 32; off > 0; off >>= 1) {
        s1 += __shfl_xor(s1, off);
        s2 += __shfl_xor(s2, off);
    }
    __shared__ float r1[4], r2[4];
    const int wv = tid >> 6, lane = tid & 63;
    if (lane == 0) { r1[wv] = s1; r2[wv] = s2; }
    __syncthreads();
    s1 = r1[0] + r1[1] + r1[2] + r1[3];
    s2 = r2[0] + r2[1] + r2[2] + r2[3];
    const float mean = s1 * (1.0f / Hc);
    const float var  = s2 * (1.0f / Hc) - mean * mean;
    const float rs = rsqrtf(var + LN_EPS);
    x.x = (x.x - mean) * rs; x.y = (x.y - mean) * rs;
    x.z = (x.z - mean) * rs; x.w = (x.w - mean) * rs;
    hr[tid] = x;
    if (hb != nullptr) {
        s16x4 o; o[0] = f2b(x.x); o[1] = f2b(x.y); o[2] = f2b(x.z); o[3] = f2b(x.w);
        *(s16x4*)&hb[row * Hc + tid * 4] = o;
    }
}

// ---------------------------------------------------------------------------
// Merged per-layer weight convert+transpose: 3072 64x64 tiles.
// ---------------------------------------------------------------------------
__global__ __launch_bounds__(256) void wconv_all_kernel(
    const float* __restrict__ Wq, const float* __restrict__ Wk,
    const float* __restrict__ Wv, const float* __restrict__ Wo,
    const float* __restrict__ W1, const float* __restrict__ W2,
    short* __restrict__ wqkv_t, short* __restrict__ wo_t,
    short* __restrict__ w1_t, short* __restrict__ w2_t)
{
    __shared__ float Ls[64][68];
    const int blk = blockIdx.x;
    const float* src; short* dst; int N, dstStride, dstRow0, tx, ty;
    if (blk < 1024) {
        const int m = blk >> 8;
        const int local = blk & 255;
        tx = local & 15; ty = local >> 4;
        N = 1024; dstStride = 1024;
        if (m == 0)      { src = Wq; dst = wqkv_t; dstRow0 = 0; }
        else if (m == 1) { src = Wk; dst = wqkv_t; dstRow0 = 1024; }
        else if (m == 2) { src = Wv; dst = wqkv_t; dstRow0 = 2048; }
        else             { src = Wo; dst = wo_t;   dstRow0 = 0; }
    } else if (blk < 2048) {
        const int local = blk - 1024;
        tx = local & 63; ty = local >> 6;
        src = W1; dst = w1_t; N = 4096; dstStride = 1024; dstRow0 = 0;
    } else {
        const int local = blk - 2048;
        tx = local & 15; ty = local >> 4;
        src = W2; dst = w2_t; N = 1024; dstStride = 4096; dstRow0 = 0;
    }
    const int n0 = tx * 64, k0 = ty * 64;
    const int tid = threadIdx.x;
    #pragma unroll
    for (int it = 0; it < 4; ++it) {
        const int idx = tid + 256 * it;
        const int r = idx >> 4, c4 = idx & 15;
        *(f32x4*)&Ls[r][c4 * 4] = *(const f32x4*)(src + (size_t)(k0 + r) * N + n0 + c4 * 4);
    }
    __syncthreads();
    #pragma unroll
    for (int it = 0; it < 2; ++it) {
        const int idx = tid + 256 * it;
        const int n = idx & 63, k8 = idx >> 6;
        s16x8 o;
        #pragma unroll
        for (int j = 0; j < 8; ++j) o[j] = f2b(Ls[k8 * 8 + j][n]);
        *(s16x8*)(dst + (size_t)(dstRow0 + n0 + n) * dstStride + k0 + k8 * 8) = o;
    }
}

// ---------------------------------------------------------------------------
// Pack QKV biases
// ---------------------------------------------------------------------------
__global__ __launch_bounds__(256) void biaspack_kernel(
    const float* __restrict__ bq, const float* __restrict__ bk,
    const float* __restrict__ bv, float* __restrict__ pb)
{
    const int idx = blockIdx.x * 256 + threadIdx.x;
    const int l = idx / 3072, j = idx % 3072;
    float v;
    if (j < 1024) v = bq[l * 1024 + j];
    else if (j < 2048) v = bk[l * 1024 + j - 1024];
    else v = bv[l * 1024 + j - 2048];
    pb[idx] = v;
}

// ---------------------------------------------------------------------------
// Heads weight pack
// ---------------------------------------------------------------------------
__global__ __launch_bounds__(256) void headspack_kernel(
    const float* __restrict__ Wps, const float* __restrict__ bps,
    const float* __restrict__ Wpr, const float* __restrict__ bpr,
    const float* __restrict__ Wpa, const float* __restrict__ bpa,
    short* __restrict__ Wha, short* __restrict__ Whb,
    float* __restrict__ biasA, float* __restrict__ biasB)
{
    const int n = blockIdx.x & 63, set = blockIdx.x >> 6;   // grid 128
    const int tid = threadIdx.x;
    if (tid == 0) {
        if (set == 0) biasA[n] = (n < 17) ? bps[n] : (n == 17 ? bpr[0] : 0.f);
        else          biasB[n] = (n < 18) ? bpa[n] : 0.f;
    }
    short* dst = (set == 0 ? Wha : Whb) + (size_t)n * 1024;
    for (int k = tid; k < 1024; k += 256) {
        float v;
        if (set == 0) v = (n < 17) ? Wps[(size_t)k * 17 + n] : (n == 17 ? Wpr[k] : 0.f);
        else          v = (n < 18) ? Wpa[(size_t)k * 18 + n] : 0.f;
        dst[k] = f2b(v);
    }
}

// ---------------------------------------------------------------------------
// Heads gather
// ---------------------------------------------------------------------------
__global__ __launch_bounds__(256) void headsgather_kernel(
    const float* __restrict__ scrA, const float* __restrict__ scrB,
    float* __restrict__ out)
{
    const int idx = blockIdx.x * 256 + threadIdx.x;
    if (idx >= 2048 * 36) return;
    const int bt = idx / 36, j = idx % 36;
    if (j < 17)      out[bt * 17 + j] = scrA[bt * 64 + j];
    else if (j < 35) out[2048 * 17 + bt * 18 + (j - 17)] = scrB[bt * 64 + (j - 17)];
    else             out[2048 * 35 + bt] = scrA[bt * 64 + 17];
}

// ---------------------------------------------------------------------------
// 128-tile bf16 GEMM (round-7/11 proven structure): 2-buffer, counted-vmcnt,
// 2 barriers, both-sides LDS swizzle, launch_bounds(256,4).
// T1: chunked XCD-aware block remap (nwg % 8 == 0 for every launch).
// VT_FUSE (QKV only): cols >= 2048 written transposed to vt[bh][d][s].
// ---------------------------------------------------------------------------
template<int BN, int DO_GELU, int OUTBF16, int VT_FUSE>
__global__ __launch_bounds__(256, 4) void gemm_bb(
    const short* __restrict__ A, const short* __restrict__ Bt,
    const float* __restrict__ bias, void* __restrict__ Cv,
    int M, int N, int K, int arm, int aro, short* __restrict__ vt)
{
    constexpr int NJ = BN / 32;
    __shared__ short As[2 * 128 * 32];
    __shared__ short Bs[2 * BN * 32];
    const int tid = threadIdx.x, lane = tid & 63, wid = tid >> 6;
    const int wr = wid >> 1, wc = wid & 1;
    const int g = lane >> 4, ql = lane & 15;

    // XCD-aware chunked remap: same-XCD hardware slots get consecutive work
    const int nwg = gridDim.x * gridDim.y;
    int wg = blockIdx.y * gridDim.x + blockIdx.x;
    wg = (wg & 7) * (nwg >> 3) + (wg >> 3);
    const int m0 = (wg / gridDim.x) * 128, n0 = (wg % gridDim.x) * BN;

    const int crow = lane >> 2;
    const int csw  = ((lane & 3) ^ ((crow >> 1) & 3)) * 8;

    const short* Ag0 = A + ((size_t)arm * (m0 + wid * 32 + crow) + aro) * K + csw;
    const short* Ag1 = A + ((size_t)arm * (m0 + wid * 32 + 16 + crow) + aro) * K + csw;
    const int a0off = (wid * 32) * 32;
    const int a1off = (wid * 32 + 16) * 32;

    const short* Bg0; const short* Bg1 = nullptr;
    int b0off = 0, b1off = 0;
    if constexpr (BN == 128) {
        Bg0 = Bt + (size_t)(n0 + wid * 32 + crow) * K + csw;
        Bg1 = Bt + (size_t)(n0 + wid * 32 + 16 + crow) * K + csw;
        b0off = (wid * 32) * 32;
        b1off = (wid * 32 + 16) * 32;
    } else {
        Bg0 = Bt + (size_t)(n0 + wid * 16 + crow) * K + csw;
        b0off = (wid * 16) * 32;
    }

    auto stage = [&](int buf, int k0) {
        short* Ab = &As[buf * (128 * 32)];
        short* Bb = &Bs[buf * (BN * 32)];
        gload16(Ag0 + k0, Ab + a0off);
        gload16(Ag1 + k0, Ab + a1off);
        gload16(Bg0 + k0, Bb + b0off);
        if constexpr (BN == 128) gload16(Bg1 + k0, Bb + b1off);
    };

    const int rslot = (g ^ ((ql >> 1) & 3)) * 8;
    const int aoffr = (wr * 64 + ql) * 32 + rslot;
    const int boffr = (wc * (BN / 2) + ql) * 32 + rslot;

    f32x4 acc[4][NJ] = {};
    stage(0, 0);
    stage(1, 32);
    int cur = 0;
    for (int k0 = 0; k0 < K; k0 += 32) {
        if (k0 + 32 < K) {
            if constexpr (BN == 128) asm volatile("s_waitcnt vmcnt(4)" ::: "memory");
            else                     asm volatile("s_waitcnt vmcnt(3)" ::: "memory");
        } else {
            asm volatile("s_waitcnt vmcnt(0)" ::: "memory");
        }
        __builtin_amdgcn_s_barrier();

        const short* Acur = &As[cur * (128 * 32)];
        const short* Bcur = &Bs[cur * (BN * 32)];
        s16x8 af[4], bfr[NJ];
        #pragma unroll
        for (int mi = 0; mi < 4; ++mi)
            af[mi] = *(const s16x8*)&Acur[aoffr + mi * (16 * 32)];
        #pragma unroll
        for (int nj = 0; nj < NJ; ++nj)
            bfr[nj] = *(const s16x8*)&Bcur[boffr + nj * (16 * 32)];

        asm volatile("s_waitcnt lgkmcnt(0)" ::: "memory");
        __builtin_amdgcn_sched_barrier(0);
        __builtin_amdgcn_s_barrier();

        if (k0 + 64 < K) stage(cur, k0 + 64);

        #pragma unroll
        for (int mi = 0; mi < 4; ++mi)
            #pragma unroll
            for (int nj = 0; nj < NJ; ++nj)
                acc[mi][nj] = __builtin_amdgcn_mfma_f32_16x16x32_bf16(
                    af[mi], bfr[nj], acc[mi][nj], 0, 0, 0);
        cur ^= 1;
    }

    #pragma unroll
    for (int mi = 0; mi < 4; ++mi) {
        #pragma unroll
        for (int nj = 0; nj < NJ; ++nj) {
            const int col = n0 + wc * (BN / 2) + nj * 16 + ql;
            const float bv = bias[col];
            float vals[4];
            #pragma unroll
            for (int r = 0; r < 4; ++r) {
                float v = acc[mi][nj][r] + bv;
                if constexpr (DO_GELU) v = gelu_tanh(v);
                vals[r] = v;
            }
            if (VT_FUSE && col >= 2048) {
                const int row0 = m0 + wr * 64 + mi * 16 + g * 4;
                const int b = row0 / Sc, s = row0 % Sc;
                const int cc = col - 2048, hh = cc >> 6, d = cc & 63;
                s16x4 o;
                #pragma unroll
                for (int r = 0; r < 4; ++r) o[r] = f2b(vals[r]);
                *(s16x4*)(vt + (((size_t)(b * NHc + hh) * 64 + d) * Sc + s)) = o;
            } else {
                #pragma unroll
                for (int r = 0; r < 4; ++r) {
                    const int row = m0 + wr * 64 + mi * 16 + g * 4 + r;
                    if constexpr (OUTBF16)
                        ((short*)Cv)[(size_t)row * N + col] = f2b(vals[r]);
                    else
                        ((float*)Cv)[(size_t)row * N + col] = vals[r];
                }
            }
        }
    }
}

// ---------------------------------------------------------------------------
// MFMA flash attention v3 (round-9 proven) + XCD-aware remap.
// ---------------------------------------------------------------------------
__global__ __launch_bounds__(256) void attn_kernel(
    const short* __restrict__ qg, const short* __restrict__ kg,
    const short* __restrict__ vtg, short* __restrict__ og, int qks)
{
    const int nqt = Sc / 64;
    const int nwg = gridDim.x;
    int blk = blockIdx.x;
    blk = (blk & 7) * (nwg >> 3) + (blk >> 3);   // same-XCD slots -> same bh group
    const int bh = blk / nqt;
    const int qt = (nqt - 1) - (blk % nqt);      // longest blocks first within group
    const int b = bh / NHc, hh = bh % NHc;
    const int tid = threadIdx.x, lane = tid & 63, w = tid >> 6;
    const int g = lane >> 4, ql = lane & 15;

    __shared__ short Ks[2][64 * 64];
    __shared__ short Vs[2][64 * 64];
    __shared__ short Qs[64][72];
    __shared__ short Ps[4][16][72];

    const size_t baseq = ((size_t)b * Sc) * qks + hh * Dc;

    #pragma unroll
    for (int i = 0; i < 2; ++i) {
        const int idx = tid + 256 * i;
        const int r = idx >> 3, c8 = idx & 7;
        *(s16x8*)&Qs[r][c8 * 8] =
            *(const s16x8*)(qg + baseq + (size_t)(qt * 64 + r) * qks + c8 * 8);
    }
    __syncthreads();
    const s16x8 bq0 = *(const s16x8*)&Qs[w * 16 + ql][g * 8];
    const s16x8 bq1 = *(const s16x8*)&Qs[w * 16 + ql][32 + g * 8];

    const int srow = lane >> 3;               // 0..7
    const int r0 = w * 8 + srow;
    const int r1 = 32 + w * 8 + srow;
    const int g0 = ((lane & 7) ^ (r0 & 7)) * 8;
    const int g1 = ((lane & 7) ^ (r1 & 7)) * 8;
    const short* kg0 = kg + baseq + (size_t)r0 * qks + g0;
    const short* kg1 = kg + baseq + (size_t)r1 * qks + g1;
    const short* vg0 = vtg + ((size_t)bh * 64 + r0) * Sc + g0;
    const short* vg1 = vtg + ((size_t)bh * 64 + r1) * Sc + g1;

    auto stageKV = [&](int buf, int kt) {
        const size_t ko = (size_t)kt * 64 * qks;
        const size_t vo = (size_t)kt * 64;
        gload16(kg0 + ko, &Ks[buf][w * 512]);
        gload16(kg1 + ko, &Ks[buf][2048 + w * 512]);
        gload16(vg0 + vo, &Vs[buf][w * 512]);
        gload16(vg1 + vo, &Vs[buf][2048 + w * 512]);
    };

    const int kx = ql & 7;
    const int gr0 = (g ^ kx) * 8;
    const int gr1 = ((4 + g) ^ kx) * 8;

    f32x4 acc_o[4] = {};
    float m = -1e30f, l = 0.f;
    const int qrow = qt * 64 + w * 16 + ql;

    stageKV(0, 0);
    for (int kt = 0; kt <= qt; ++kt) {
        const int buf = kt & 1;
        if (kt < qt) {
            stageKV(buf ^ 1, kt + 1);
            asm volatile("s_waitcnt vmcnt(4)" ::: "memory");
        } else {
            asm volatile("s_waitcnt vmcnt(0)" ::: "memory");
        }
        __builtin_amdgcn_s_barrier();

        s16x8 ka0[4], ka1[4], vv0[4], vv1[4];
        #pragma unroll
        for (int mi = 0; mi < 4; ++mi) {
            ka0[mi] = *(const s16x8*)&Ks[buf][(mi * 16 + ql) * 64 + gr0];
            ka1[mi] = *(const s16x8*)&Ks[buf][(mi * 16 + ql) * 64 + gr1];
            vv0[mi] = *(const s16x8*)&Vs[buf][(mi * 16 + ql) * 64 + gr0];
            vv1[mi] = *(const s16x8*)&Vs[buf][(mi * 16 + ql) * 64 + gr1];
        }
        asm volatile("s_waitcnt lgkmcnt(0)" ::: "memory");
        __builtin_amdgcn_sched_barrier(0);
        __builtin_amdgcn_s_barrier();

        f32x4 sacc[4] = {};
        #pragma unroll
        for (int mi = 0; mi < 4; ++mi) {
            sacc[mi] = __builtin_amdgcn_mfma_f32_16x16x32_bf16(ka0[mi], bq0, sacc[mi], 0, 0, 0);
            sacc[mi] = __builtin_amdgcn_mfma_f32_16x16x32_bf16(ka1[mi], bq1, sacc[mi], 0, 0, 0);
        }

        float pv[16];
        float pm = -1e30f;
        #pragma unroll
        for (int mi = 0; mi < 4; ++mi)
            #pragma unroll
            for (int r = 0; r < 4; ++r) {
                const int kv = kt * 64 + mi * 16 + g * 4 + r;
                const float s = (kv <= qrow) ? sacc[mi][r] * 0.125f : -1e30f;
                pv[mi * 4 + r] = s;
                pm = fmaxf(pm, s);
            }
        pm = fmaxf(pm, __shfl_xor(pm, 16));
        pm = fmaxf(pm, __shfl_xor(pm, 32));
        const float m2 = fmaxf(m, pm);
        const float corr = __expf(m - m2);
        m = m2;
        float ps = 0.f;
        #pragma unroll
        for (int i = 0; i < 16; ++i) { pv[i] = __expf(pv[i] - m2); ps += pv[i]; }
        ps += __shfl_xor(ps, 16);
        ps += __shfl_xor(ps, 32);
        l = l * corr + ps;

        #pragma unroll
        for (int mi = 0; mi < 4; ++mi) {
            s16x4 pw;
            #pragma unroll
            for (int r = 0; r < 4; ++r) pw[r] = f2b(pv[mi * 4 + r]);
            *(s16x4*)&Ps[w][ql][mi * 16 + g * 4] = pw;
        }

        float corr_r[4];
        #pragma unroll
        for (int r = 0; r < 4; ++r) corr_r[r] = __shfl(corr, g * 4 + r);
        #pragma unroll
        for (int nj = 0; nj < 4; ++nj)
            #pragma unroll
            for (int r = 0; r < 4; ++r) acc_o[nj][r] *= corr_r[r];

        const s16x8 pa0 = *(const s16x8*)&Ps[w][ql][g * 8];
        const s16x8 pa1 = *(const s16x8*)&Ps[w][ql][32 + g * 8];
        #pragma unroll
        for (int nj = 0; nj < 4; ++nj) {
            acc_o[nj] = __builtin_amdgcn_mfma_f32_16x16x32_bf16(pa0, vv0[nj], acc_o[nj], 0, 0, 0);
            acc_o[nj] = __builtin_amdgcn_mfma_f32_16x16x32_bf16(pa1, vv1[nj], acc_o[nj], 0, 0, 0);
        }
    }

    const float rl = 1.0f / l;
    float rl_r[4];
    #pragma unroll
    for (int r = 0; r < 4; ++r) rl_r[r] = __shfl(rl, g * 4 + r);
    const size_t baseo = ((size_t)b * Sc) * Hc + hh * Dc;
    #pragma unroll
    for (int nj = 0; nj < 4; ++nj)
        #pragma unroll
        for (int r = 0; r < 4; ++r) {
            const int qr = qt * 64 + w * 16 + g * 4 + r;
            og[baseo + (size_t)qr * Hc + nj * 16 + ql] = f2b(acc_o[nj][r] * rl_r[r]);
        }
}

// ---------------------------------------------------------------------------
extern "C" void kernel_launch(void* const* d_in, const int* in_sizes, int n_in,
                              void* d_out, int out_size, void* d_ws, size_t ws_size,
                              hipStream_t stream)
{
    const float* states = (const float*)d_in[0];
    const float* rtg    = (const float*)d_in[1];
    const int*   timesteps = (const int*)d_in[2];
    const int*   actions   = (const int*)d_in[3];
    const float* ett  = (const float*)d_in[5];
    const float* eat  = (const float*)d_in[6];
    const float* Wrtg = (const float*)d_in[7];
    const float* brtg = (const float*)d_in[8];
    const float* Wst  = (const float*)d_in[9];
    const float* bst  = (const float*)d_in[10];
    const float* Wq = (const float*)d_in[11];
    const float* bq = (const float*)d_in[12];
    const float* Wk = (const float*)d_in[13];
    const float* bk = (const float*)d_in[14];
    const float* Wv = (const float*)d_in[15];
    const float* bv = (const float*)d_in[16];
    const float* Wo = (const float*)d_in[17];
    const float* bo = (const float*)d_in[18];
    const float* W1 = (const float*)d_in[19];
    const float* b1 = (const float*)d_in[20];
    const float* W2 = (const float*)d_in[21];
    const float* b2 = (const float*)d_in[22];
    const float* Wpr = (const float*)d_in[23];
    const float* bpr = (const float*)d_in[24];
    const float* Wps = (const float*)d_in[25];
    const float* bps = (const float*)d_in[26];
    const float* Wpa = (const float*)d_in[27];
    const float* bpa = (const float*)d_in[28];
    float* out = (float*)d_out;

    char* wsb = (char*)d_ws;
    const size_t MH = (size_t)Mrows * Hc;            // 6,291,456 elems
    const int nAttnBlk = Bc * NHc * (Sc / 64);       // 1536

    const size_t off_h    = 0;                        // f32  [M][H]
    const size_t off_hb   = off_h    + MH * 4;        // bf16 [M][H]
    const size_t off_qkv  = off_hb   + MH * 2;        // bf16 [M][3H]
    const size_t off_vt   = off_qkv  + MH * 6;        // bf16 [BH][D][S]
    const size_t off_ob   = off_vt   + MH * 2;        // bf16 [M][H]
    const size_t off_rb   = off_ob   + MH * 2;        // bf16 [M][H] (+ heads f32 scratch)
    const size_t off_wl   = off_rb   + MH * 4;        // bf16 per-layer weights
    const size_t wl_qkv   = 0;
    const size_t wl_wo    = wl_qkv + (size_t)3072 * 1024 * 2;
    const size_t wl_w1    = wl_wo  + (size_t)1024 * 1024 * 2;
    const size_t wl_w2    = wl_w1  + (size_t)4096 * 1024 * 2;
    const size_t wl_bytes = wl_w2  + (size_t)1024 * 4096 * 2;
    const size_t off_pb   = off_wl + wl_bytes;        // f32 [L][3072]

    float* h   = (float*)(wsb + off_h);
    short* hb  = (short*)(wsb + off_hb);
    short* qkv = (short*)(wsb + off_qkv);
    short* vt  = (short*)(wsb + off_vt);
    short* ob  = (short*)(wsb + off_ob);
    short* rb  = (short*)(wsb + off_rb);           // bf16 residual buffer
    short* gb  = qkv;                              // bf16 [M][4096], spans qkv..vt
    short* wqkv_t = (short*)(wsb + off_wl + wl_qkv);
    short* wo_t   = (short*)(wsb + off_wl + wl_wo);
    short* w1_t   = (short*)(wsb + off_wl + wl_w1);
    short* w2_t   = (short*)(wsb + off_wl + wl_w2);
    float* pb     = (float*)(wsb + off_pb);
    short* Wha   = ob;                             // heads scratch (ob free at end)
    short* Whb   = ob + 64 * 1024;
    float* biasA = (float*)(ob + 2 * 64 * 1024);
    float* biasB = biasA + 64;
    float* scrA  = (float*)(wsb + off_rb + MH * 2);   // f32 [2048][64] x2, after rb
    float* scrB  = scrA + 2048 * 64;

    biaspack_kernel<<<Lc * 12, 256, 0, stream>>>(bq, bk, bv, pb);
    embed_kernel<<<Bc * Tc, 256, 0, stream>>>(states, rtg, timesteps, actions,
                                              ett, eat, Wrtg, brtg, Wst, bst, h);
    resln_kernel<<<Mrows, 256, 0, stream>>>(h, nullptr, hb);

    const dim3 gQKV(3072 / 128, Mrows / 128);     // (24,48)  nwg=1152
    const dim3 gFF1(FFc / 128, Mrows / 128);      // (32,48)  nwg=1536
    const dim3 gN1K(1024 / 128, Mrows / 128);     // (8,48)   nwg=384

    for (int i = 0; i < Lc; ++i) {
        const size_t wofH = (size_t)i * Hc * Hc;
        const size_t wofF = (size_t)i * Hc * FFc;
        wconv_all_kernel<<<3072, 256, 0, stream>>>(
            Wq + wofH, Wk + wofH, Wv + wofH, Wo + wofH, W1 + wofF, W2 + wofF,
            wqkv_t, wo_t, w1_t, w2_t);

        // QKV with fused V^T emission (V region bypasses qkv buffer)
        gemm_bb<128,0,1,1><<<gQKV, 256, 0, stream>>>(hb, wqkv_t, pb + i * 3072, qkv, Mrows, 3072, 1024, 1, 0, vt);
        attn_kernel<<<nAttnBlk, 256, 0, stream>>>(qkv, qkv + 1024, vt, ob, 3072);
        gemm_bb<128,0,1,0><<<gN1K, 256, 0, stream>>>(ob, wo_t, bo + i * Hc, rb, Mrows, 1024, 1024, 1, 0, nullptr);
        resln_kernel<<<Mrows, 256, 0, stream>>>(h, rb, hb);

        gemm_bb<128,1,1,0><<<gFF1, 256, 0, stream>>>(hb, w1_t, b1 + i * FFc, gb, Mrows, 4096, 1024, 1, 0, nullptr);
        gemm_bb<128,0,1,0><<<gN1K, 256, 0, stream>>>(gb, w2_t, b2 + i * Hc, rb, Mrows, 1024, 4096, 1, 0, nullptr);
        resln_kernel<<<Mrows, 256, 0, stream>>>(h, rb, hb);
    }

    // heads: row(hb) = 3*m + {2:h_a, 1:h_s}
    headspack_kernel<<<128, 256, 0, stream>>>(Wps, bps, Wpr, bpr, Wpa, bpa,
                                              Wha, Whb, biasA, biasB);
    gemm_bb<64,0,0,0><<<dim3(1, 16), 256, 0, stream>>>(hb, Wha, biasA, scrA, 2048, 64, 1024, 3, 2, nullptr);
    gemm_bb<64,0,0,0><<<dim3(1, 16), 256, 0, stream>>>(hb, Whb, biasB, scrB, 2048, 64, 1024, 3, 1, nullptr);
    headsgather_kernel<<<288, 256, 0, stream>>>(scrA, scrB, out);
}